// Round 2
// 193.702 us; speedup vs baseline: 1.0184x; 1.0184x over previous
//
#include <hip/hip_runtime.h>
#include <hip/hip_bf16.h>

// SparseDiffusionModel on MI355X — dtype-adaptive (fp32 confirmed active).
//
// Algebra: everything between `features` and attention is affine in features;
// query is one token/batch:
//   score[i,h] = f_i . u[b,h] + cq[b,h],  u_h = Wtok@(Wk@(Wik[:,hblk]@q_h))/sqrt32
//   ctx_h = ((wbar_h@Wtok+btok)@Wv+bv)@Wiv[:,hblk]+biv, wbar = softmax-wtd mean.
//
// Round-9 (resubmit; round-1 bench was an infra failure, no counters):
// harness reset floor (~150-165us of 268MB poison + restores) is untouchable;
// kF fusion to one pass (r8) gained ~0 -> kF is NOT BW-bound, it's per-block
// setup + per-segment epilogue bound (main loop is only 8 iters/group).
// This round: (a) kF blocks grow to 256 tokens x 512 threads (grid 512) ->
// half the setups/epilogues per byte, same occupancy (16 waves/CU); side
// effect: kE slot lists halve. (b) kE's final 3-output reduction:
// 24 __syncthreads tree -> 1 barrier via wave shfl reduce.
//
// ws (floats): flag | cnt[64 i32] | slot[64*32 i32] | u[32768] | cq[256]
//   | l_ovf[256] | w_ovf[32768] | lpart[8192] | wpart[2048*512 bf16]

typedef unsigned short ushort_t;
typedef unsigned int uint_t;
typedef unsigned long long ull_t;

#define NB 64
#define CENC 128
#define HID 512
#define RSQRT32 0.17677669529663689f

#define WS_FLAG   0
#define WS_CNT    64
#define WS_SLOT   128
#define WS_U      2176
#define WS_CQ     34944
#define WS_LOVF   35200
#define WS_WOVF   35456
#define WS_LPART  68224
#define WS_WPART  76416

__device__ __forceinline__ float blo(uint_t u){ return __uint_as_float(u << 16); }
__device__ __forceinline__ float bhi(uint_t u){ return __uint_as_float(u & 0xffff0000u); }
__device__ __forceinline__ float bf2f(ushort_t h){ return __uint_as_float(((uint_t)h) << 16); }
__device__ __forceinline__ ushort_t f2bf(float f){
    uint_t u = __float_as_uint(f);
    u += 0x7fffu + ((u >> 16) & 1u);   // RNE
    return (ushort_t)(u >> 16);
}

template<bool BF16> struct Ld;
template<> struct Ld<true> {
    static __device__ __forceinline__ float at(const void* p, long i) {
        return __uint_as_float(((uint_t)((const ushort_t*)p)[i]) << 16);
    }
};
template<> struct Ld<false> {
    static __device__ __forceinline__ float at(const void* p, long i) {
        return ((const float*)p)[i];
    }
};

// dtype detection on first 4096 ushorts of features (see r2/r3 notes).
__device__ int detect_bf16(const ushort_t* f, int tid, int* sh2) {
    if (tid == 0) { sh2[0] = 0; sh2[1] = 0; }
    __syncthreads();
    int myb = 0, myz = 0;
    for (int i = tid; i < 4096; i += 256) {
        ushort_t v = f[i];
        if (((v >> 7) & 0xff) >= 140) myb = 1;
        if (!(i & 1) && v == 0) myz++;
    }
    if (myb) atomicOr(&sh2[0], 1);
    atomicAdd(&sh2[1], myz);
    __syncthreads();
    return (sh2[0] || sh2[1] > 1024) ? 0 : 1;   // 1 = true bf16
}

// ---------------------------------------------------------------------------
// kA: per batch (64 x 256) — unchanged.
template<bool BF16>
__device__ void kA_impl(int b, int tid,
    const void* y_t, const int* t,
    const void* Wt, const void* bt, const void* Win, const void* bin_,
    const void* Wq, const void* bq, const void* Wiq, const void* biq,
    const void* Wtok, const void* btok, const void* Wk, const void* bk,
    const void* Wik, const void* bik, float* ws, float* sh)
{
    using L = Ld<BF16>;
    float* emb = sh;            // 64
    float* y   = sh + 64;       // 512
    float* p2  = sh + 576;      // 256
    float* q0  = sh + 832;      // 128
    float* qL  = sh + 960;      // 128
    float* tb  = sh + 1088;     // 128
    float* t1a = sh + 1216;     // 512
    float* t2a = sh + 1728;     // 512
    float* p1k = sh + 2240;     // 1024
    float* u_out  = ws + WS_U;
    float* cq_out = ws + WS_CQ;

    const int c = tid & 127, pair = tid >> 7;

    for (int i = tid; i < 512; i += 256) ws[WS_WOVF + b*512 + i] = 0.f;
    if (tid < 4) ws[WS_LOVF + b*4 + tid] = 0.f;
    if (tid == 0) ((int*)ws)[WS_CNT + b] = 0;

    if (tid < 32) {
        float fr = __expf(-(float)tid * 0.28782313662425576f); // ln(1e4)/32
        float arg = (float)t[b] * fr;
        emb[tid]      = sinf(arg);
        emb[tid + 32] = cosf(arg);
    }
    __syncthreads();

    float yt0 = L::at(y_t, b*3+0), yt1 = L::at(y_t, b*3+1), yt2 = L::at(y_t, b*3+2);
    #pragma unroll
    for (int rep = 0; rep < 2; rep++) {
        int o = tid + rep*256;
        float acc = L::at(bt, o);
        #pragma unroll
        for (int k = 0; k < 64; k++) acc += emb[k] * L::at(Wt, (long)k*512 + o);
        acc = fmaxf(acc, 0.f);
        y[o] = acc + L::at(bin_, o) + yt0*L::at(Win, o) + yt1*L::at(Win, 512+o)
             + yt2*L::at(Win, 1024+o);
    }
    __syncthreads();
    {   // q0 = y @ Wq + bq
        float acc = 0.f;
        #pragma unroll
        for (int k4 = 0; k4 < 256; k4 += 4) {
            int kk = pair*256 + k4;
            float4 y4 = *(const float4*)&y[kk];
            acc += y4.x*L::at(Wq,(long)kk*128+c)     + y4.y*L::at(Wq,(long)(kk+1)*128+c)
                 + y4.z*L::at(Wq,(long)(kk+2)*128+c) + y4.w*L::at(Wq,(long)(kk+3)*128+c);
        }
        p2[pair*128 + c] = acc;
    }
    __syncthreads();
    if (tid < 128) q0[tid] = p2[tid] + p2[128+tid] + L::at(bq, tid);
    __syncthreads();
    {   // qL = q0 @ Wiq + biq
        float acc = 0.f;
        #pragma unroll
        for (int k4 = 0; k4 < 64; k4 += 4) {
            int kk = pair*64 + k4;
            float4 q4 = *(const float4*)&q0[kk];
            acc += q4.x*L::at(Wiq,(long)kk*128+c)     + q4.y*L::at(Wiq,(long)(kk+1)*128+c)
                 + q4.z*L::at(Wiq,(long)(kk+2)*128+c) + q4.w*L::at(Wiq,(long)(kk+3)*128+c);
        }
        p2[pair*128 + c] = acc;
    }
    __syncthreads();
    if (tid < 128) qL[tid] = p2[tid] + p2[128+tid] + L::at(biq, tid);
    __syncthreads();
    {   // tb = btok @ Wk + bk
        float acc = 0.f;
        #pragma unroll
        for (int k4 = 0; k4 < 64; k4 += 4) {
            int kk = pair*64 + k4;
            acc += L::at(btok,kk)  *L::at(Wk,(long)kk*128+c)
                 + L::at(btok,kk+1)*L::at(Wk,(long)(kk+1)*128+c)
                 + L::at(btok,kk+2)*L::at(Wk,(long)(kk+2)*128+c)
                 + L::at(btok,kk+3)*L::at(Wk,(long)(kk+3)*128+c);
        }
        p2[pair*128 + c] = acc;
    }
    __syncthreads();
    if (tid < 128) tb[tid] = p2[tid] + p2[128+tid] + L::at(bk, tid);
    __syncthreads();
    {   // t1[h][c] = Wik[c, h*32+j] . qL_h
        float a0=0.f, a1=0.f, a2=0.f, a3=0.f;
        #pragma unroll
        for (int j = 0; j < 16; j++) {
            int jj = pair*16 + j;
            a0 += L::at(Wik,(long)c*128 +  0 + jj) * qL[ 0 + jj];
            a1 += L::at(Wik,(long)c*128 + 32 + jj) * qL[32 + jj];
            a2 += L::at(Wik,(long)c*128 + 64 + jj) * qL[64 + jj];
            a3 += L::at(Wik,(long)c*128 + 96 + jj) * qL[96 + jj];
        }
        p1k[pair*512 +   0 + c] = a0; p1k[pair*512 + 128 + c] = a1;
        p1k[pair*512 + 256 + c] = a2; p1k[pair*512 + 384 + c] = a3;
    }
    __syncthreads();
    t1a[tid]     = p1k[tid]     + p1k[512+tid];
    t1a[tid+256] = p1k[tid+256] + p1k[768+tid];
    __syncthreads();
    {   // cq per head: wave h
        int hw = tid >> 6, lam = tid & 63;
        float r = tb[lam]*t1a[hw*128+lam] + tb[lam+64]*t1a[hw*128+64+lam];
        if (lam < 32) r += L::at(bik, hw*32+lam) * qL[hw*32+lam];
        #pragma unroll
        for (int mm = 1; mm < 64; mm <<= 1) r += __shfl_xor(r, mm, 64);
        if (lam == 0) cq_out[b*4 + hw] = r * RSQRT32;
    }
    {   // t2[h][c] = Wk[c,:] . t1[h]
        float a0=0.f, a1=0.f, a2=0.f, a3=0.f;
        #pragma unroll
        for (int k4 = 0; k4 < 64; k4 += 4) {
            int kk = pair*64 + k4;
            float wa = L::at(Wk,(long)c*128+kk),   wbv = L::at(Wk,(long)c*128+kk+1);
            float wc = L::at(Wk,(long)c*128+kk+2), wd  = L::at(Wk,(long)c*128+kk+3);
            float4 t0 = *(const float4*)&t1a[kk],     t1v = *(const float4*)&t1a[128+kk];
            float4 t2v = *(const float4*)&t1a[256+kk], t3v = *(const float4*)&t1a[384+kk];
            a0 += wa*t0.x + wbv*t0.y + wc*t0.z + wd*t0.w;
            a1 += wa*t1v.x + wbv*t1v.y + wc*t1v.z + wd*t1v.w;
            a2 += wa*t2v.x + wbv*t2v.y + wc*t2v.z + wd*t2v.w;
            a3 += wa*t3v.x + wbv*t3v.y + wc*t3v.z + wd*t3v.w;
        }
        p1k[pair*512 +   0 + c] = a0; p1k[pair*512 + 128 + c] = a1;
        p1k[pair*512 + 256 + c] = a2; p1k[pair*512 + 384 + c] = a3;
    }
    __syncthreads();
    t2a[tid]     = p1k[tid]     + p1k[512+tid];
    t2a[tid+256] = p1k[tid+256] + p1k[768+tid];
    __syncthreads();
    {   // u[h][c] = Wtok[c,:] . t2[h]
        float a0=0.f, a1=0.f, a2=0.f, a3=0.f;
        #pragma unroll
        for (int k4 = 0; k4 < 64; k4 += 4) {
            int kk = pair*64 + k4;
            float wa = L::at(Wtok,(long)c*128+kk),   wbv = L::at(Wtok,(long)c*128+kk+1);
            float wc = L::at(Wtok,(long)c*128+kk+2), wd  = L::at(Wtok,(long)c*128+kk+3);
            float4 t0 = *(const float4*)&t2a[kk],     t1v = *(const float4*)&t2a[128+kk];
            float4 t2v = *(const float4*)&t2a[256+kk], t3v = *(const float4*)&t2a[384+kk];
            a0 += wa*t0.x + wbv*t0.y + wc*t0.z + wd*t0.w;
            a1 += wa*t1v.x + wbv*t1v.y + wc*t1v.z + wd*t1v.w;
            a2 += wa*t2v.x + wbv*t2v.y + wc*t2v.z + wd*t2v.w;
            a3 += wa*t3v.x + wbv*t3v.y + wc*t3v.z + wd*t3v.w;
        }
        p1k[pair*512 +   0 + c] = a0; p1k[pair*512 + 128 + c] = a1;
        p1k[pair*512 + 256 + c] = a2; p1k[pair*512 + 384 + c] = a3;
    }
    __syncthreads();
    u_out[b*512 + tid]     = (p1k[tid]     + p1k[512+tid]) * RSQRT32;
    u_out[b*512 + tid+256] = (p1k[tid+256] + p1k[768+tid]) * RSQRT32;
}

__global__ __launch_bounds__(256) void kA(
    const ushort_t* __restrict__ fraw,
    const void* y_t, const int* t,
    const void* Wt, const void* bt, const void* Win, const void* bin_,
    const void* Wq, const void* bq, const void* Wiq, const void* biq,
    const void* Wtok, const void* btok, const void* Wk, const void* bk,
    const void* Wik, const void* bik, float* ws)
{
    __shared__ int sh2[2];
    __shared__ float sh[3264];
    int flag = detect_bf16(fraw, threadIdx.x, sh2);
    if (blockIdx.x == 0 && threadIdx.x == 0) *(int*)(ws + WS_FLAG) = flag;
    if (flag) kA_impl<true >(blockIdx.x, threadIdx.x, y_t,t,Wt,bt,Win,bin_,Wq,bq,
                             Wiq,biq,Wtok,btok,Wk,bk,Wik,bik, ws, sh);
    else      kA_impl<false>(blockIdx.x, threadIdx.x, y_t,t,Wt,bt,Win,bin_,Wq,bq,
                             Wiq,biq,Wtok,btok,Wk,bk,Wik,bik, ws, sh);
}

// ---------------------------------------------------------------------------
// kF: SINGLE-PASS streaming kernel (512 blocks x 512 threads, 256 tok/block).
// 32 groups x 16 lanes; lane qq owns channels [8qq,8qq+8); per token:
// coalesced 32B f-load, dot vs u (8 named float4), shfl_xor(16) score tree,
// all-lane exp, acc[h] += e_h*f into 8 named float4 accumulators.
// 256 tok/block halves per-block setup + per-segment epilogue count vs r8.
__device__ __forceinline__ float dot8(float4 fa, float4 fb, float4 ua, float4 ub) {
    return fa.x*ua.x + fa.y*ua.y + fa.z*ua.z + fa.w*ua.w
         + fb.x*ub.x + fb.y*ub.y + fb.z*ub.z + fb.w*ub.w;
}
__device__ __forceinline__ void f4fma(float4& a, float e, float4 f) {
    a.x += e*f.x; a.y += e*f.y; a.z += e*f.z; a.w += e*f.w;
}
__device__ __forceinline__ void f4xr(float4& v, int m) {
    v.x += __shfl_xor(v.x, m, 64); v.y += __shfl_xor(v.y, m, 64);
    v.z += __shfl_xor(v.z, m, 64); v.w += __shfl_xor(v.w, m, 64);
}

template<bool BF16>
__device__ void kF_impl(const void* F, const int* __restrict__ batch_idx,
                        float* __restrict__ ws, int blk)
{
    __shared__ float ppw[8*512];      // per-wave combined w partials (16KB)
    __shared__ float red[32];         // [wave][4 heads] l partials
    __shared__ int lb[256];
    __shared__ int starts[257];
    __shared__ ull_t smask[4];
    __shared__ int nsegs;
    __shared__ int segslot[2];

    const int base = blk * 256;
    const int tau = threadIdx.x;
    const float* u   = ws + WS_U;
    const float* cqg = ws + WS_CQ;
    int* cnt      = (int*)ws + WS_CNT;
    int* slotlist = (int*)ws + WS_SLOT;
    float* l_ovf  = ws + WS_LOVF;
    float* w_ovf  = ws + WS_WOVF;
    float* lpart  = ws + WS_LPART;
    ushort_t* wpart = (ushort_t*)(ws + WS_WPART);

    if (tau < 256) lb[tau] = batch_idx[base + tau];
    __syncthreads();
    bool isstart = (tau < 256) && (tau == 0 || lb[tau] != lb[tau-1]);
    ull_t m = __ballot(isstart);
    const int wv = tau >> 6, lane = tau & 63;
    if (wv < 4 && lane == 0) smask[wv] = m;
    __syncthreads();
    if (isstart) {
        int rank = __popcll(m & ((1ull << lane) - 1ull));
        #pragma unroll
        for (int w = 0; w < 4; w++) if (w < wv) rank += __popcll(smask[w]);
        starts[rank] = tau;
    }
    if (tau == 0) nsegs = __popcll(smask[0]) + __popcll(smask[1])
                        + __popcll(smask[2]) + __popcll(smask[3]);
    __syncthreads();
    const int nseg = nsegs;
    if (tau < 2) {
        int ss = -1;
        if (tau < nseg) {
            int bb = lb[starts[tau]];
            int idx = atomicAdd(&cnt[bb], 1);
            if (idx < 32) { slotlist[bb*32 + idx] = blk*2 + tau; ss = blk*2 + tau; }
        }
        segslot[tau] = ss;
    }
    __syncthreads();

    const int qq = tau & 15, grp = tau >> 4;   // grp in block (0..31)

    for (int s = 0; s < nseg; s++) {
        const int lo = starts[s];
        const int hi = (s + 1 < nseg) ? starts[s+1] : 256;
        const int b  = lb[lo];
        const int slot = (s < 2) ? segslot[s] : -1;

        const float* ub = u + b*512 + qq*8;
        float4 u0a = *(const float4*)(ub + 0),   u0b = *(const float4*)(ub + 4);
        float4 u1a = *(const float4*)(ub + 128), u1b = *(const float4*)(ub + 132);
        float4 u2a = *(const float4*)(ub + 256), u2b = *(const float4*)(ub + 260);
        float4 u3a = *(const float4*)(ub + 384), u3b = *(const float4*)(ub + 388);
        float4 cqr = *(const float4*)(cqg + b*4);

        float4 zz = make_float4(0.f, 0.f, 0.f, 0.f);
        float4 a0a=zz,a0b=zz,a1a=zz,a1b=zz,a2a=zz,a2b=zz,a3a=zz,a3b=zz;
        float l0=0.f, l1=0.f, l2=0.f, l3=0.f;

        #pragma unroll 2
        for (int tok = lo + grp; tok < hi; tok += 32) {
            float4 fa, fb;
            if (BF16) {
                uint4 v = *(const uint4*)((const ushort_t*)F + ((long)(base+tok) << 7) + (qq << 3));
                fa.x=blo(v.x); fa.y=bhi(v.x); fa.z=blo(v.y); fa.w=bhi(v.y);
                fb.x=blo(v.z); fb.y=bhi(v.z); fb.z=blo(v.w); fb.w=bhi(v.w);
            } else {
                const float4* fp = (const float4*)((const float*)F + ((long)(base+tok) << 7) + (qq << 3));
                fa = fp[0]; fb = fp[1];
            }
            float p0 = dot8(fa, fb, u0a, u0b);
            float p1 = dot8(fa, fb, u1a, u1b);
            float p2 = dot8(fa, fb, u2a, u2b);
            float p3 = dot8(fa, fb, u3a, u3b);
            #pragma unroll
            for (int mm = 1; mm < 16; mm <<= 1) {
                p0 += __shfl_xor(p0, mm, 16);
                p1 += __shfl_xor(p1, mm, 16);
                p2 += __shfl_xor(p2, mm, 16);
                p3 += __shfl_xor(p3, mm, 16);
            }
            // every lane of the 16-group now holds the token's 4 scores
            float e0 = __expf(fminf(p0 + cqr.x, 30.f));
            float e1 = __expf(fminf(p1 + cqr.y, 30.f));
            float e2 = __expf(fminf(p2 + cqr.z, 30.f));
            float e3 = __expf(fminf(p3 + cqr.w, 30.f));
            l0 += e0; l1 += e1; l2 += e2; l3 += e3;
            f4fma(a0a, e0, fa); f4fma(a0b, e0, fb);
            f4fma(a1a, e1, fa); f4fma(a1b, e1, fb);
            f4fma(a2a, e2, fa); f4fma(a2b, e2, fb);
            f4fma(a3a, e3, fa); f4fma(a3b, e3, fb);
        }

        // l: identical across each group's 16 lanes; xor(16)+xor(32) sums the
        // wave's 4 groups (each counted once).
        l0 += __shfl_xor(l0, 16, 64); l1 += __shfl_xor(l1, 16, 64);
        l2 += __shfl_xor(l2, 16, 64); l3 += __shfl_xor(l3, 16, 64);
        l0 += __shfl_xor(l0, 32, 64); l1 += __shfl_xor(l1, 32, 64);
        l2 += __shfl_xor(l2, 32, 64); l3 += __shfl_xor(l3, 32, 64);
        if (lane == 0) *(float4*)&red[wv*4] = make_float4(l0, l1, l2, l3);

        // acc: combine the wave's 4 groups (same channel slice per qq).
        f4xr(a0a,16); f4xr(a0b,16); f4xr(a1a,16); f4xr(a1b,16);
        f4xr(a2a,16); f4xr(a2b,16); f4xr(a3a,16); f4xr(a3b,16);
        f4xr(a0a,32); f4xr(a0b,32); f4xr(a1a,32); f4xr(a1b,32);
        f4xr(a2a,32); f4xr(a2b,32); f4xr(a3a,32); f4xr(a3b,32);
        if (lane < 16) {   // one group's worth of lanes per wave writes
            float* pr = ppw + wv*512 + qq*8;
            *(float4*)(pr +   0) = a0a; *(float4*)(pr +   4) = a0b;
            *(float4*)(pr + 128) = a1a; *(float4*)(pr + 132) = a1b;
            *(float4*)(pr + 256) = a2a; *(float4*)(pr + 260) = a2b;
            *(float4*)(pr + 384) = a3a; *(float4*)(pr + 388) = a3b;
        }
        __syncthreads();   // ppw + red ready

        if (tau < 4) {
            float ls = red[tau]    + red[4+tau]  + red[8+tau]  + red[12+tau]
                     + red[16+tau] + red[20+tau] + red[24+tau] + red[28+tau];
            if (slot >= 0) lpart[slot*4 + tau] = ls;
            else atomicAdd(&l_ovf[b*4 + tau], ls);
        }
        {   // flat h*128+ch, 512 values with 512 threads
            int i = tau;
            float v = ppw[i]          + ppw[512 + i]  + ppw[1024 + i] + ppw[1536 + i]
                    + ppw[2048 + i]   + ppw[2560 + i] + ppw[3072 + i] + ppw[3584 + i];
            if (slot >= 0) wpart[(long)slot*512 + i] = f2bf(v);
            else atomicAdd(&w_ovf[b*512 + i], v);
        }
        __syncthreads();   // ppw/red reuse next segment
    }
}

__global__ __launch_bounds__(512, 4) void kF(
    const void* __restrict__ features, const int* __restrict__ batch_idx,
    float* __restrict__ ws)
{
    if (*(const int*)(ws + WS_FLAG)) kF_impl<true >(features, batch_idx, ws, blockIdx.x);
    else                             kF_impl<false>(features, batch_idx, ws, blockIdx.x);
}

// ---------------------------------------------------------------------------
// kE: per batch (64 x 256) — final 3-output reduction now 1 barrier (was 24).
template<bool BF16>
__device__ void kE_impl(int b, int tid, float* ws,
    const void* Wtok, const void* btok, const void* Wv, const void* bv,
    const void* Wiv, const void* biv, const void* Wo, const void* bo,
    const void* Wco, const void* bco, const void* Wout, const void* bout,
    void* out, float* sh, int* shi)
{
    using L = Ld<BF16>;
    float* wb   = sh;            // 512
    float* s1a  = sh + 512;      // 512
    float* s2a  = sh + 1024;     // 512
    float* ctxa = sh + 1536;     // 128
    float* aoa  = sh + 1664;     // 128
    float* y2a  = sh + 1792;     // 512
    float* p1k  = sh + 2304;     // 1024
    float* linv = sh + 3328;     // 4

    const int c = tid & 127, pair = tid >> 7;
    const int* cnti = (const int*)ws;
    const ushort_t* wpart = (const ushort_t*)(ws + WS_WPART);

    int n = cnti[WS_CNT + b]; if (n > 32) n = 32;
    if (tid < 32) shi[tid] = (tid < n) ? cnti[WS_SLOT + b*32 + tid] : 0;
    __syncthreads();

    float a0 = 0.f, a1 = 0.f, lac = 0.f;
    for (int i = 0; i < n; i++) {
        int s = shi[i];
        a0 += bf2f(wpart[(long)s*512 + tid]);
        a1 += bf2f(wpart[(long)s*512 + tid + 256]);
    }
    if (tid < 4) for (int i = 0; i < n; i++) lac += ws[WS_LPART + shi[i]*4 + tid];
    a0 += ws[WS_WOVF + b*512 + tid];
    a1 += ws[WS_WOVF + b*512 + tid + 256];
    if (tid < 4) {
        lac += ws[WS_LOVF + b*4 + tid];
        linv[tid] = (lac > 1e-30f) ? 1.f/lac : 0.f;
    }
    __syncthreads();
    wb[tid]     = a0 * linv[tid >> 7];
    wb[tid+256] = a1 * linv[(tid+256) >> 7];
    __syncthreads();

    {   // s1[h][c] = wbar_h @ Wtok[:,c]
        float b0=0.f,b1=0.f,b2=0.f,b3=0.f;
        #pragma unroll
        for (int k4 = 0; k4 < 64; k4 += 4) {
            int kk = pair*64 + k4;
            float wa = L::at(Wtok,(long)kk*128+c),     wbv = L::at(Wtok,(long)(kk+1)*128+c);
            float wc = L::at(Wtok,(long)(kk+2)*128+c), wd  = L::at(Wtok,(long)(kk+3)*128+c);
            float4 w0 = *(const float4*)&wb[kk],     w1 = *(const float4*)&wb[128+kk];
            float4 w2 = *(const float4*)&wb[256+kk], w3 = *(const float4*)&wb[384+kk];
            b0 += wa*w0.x + wbv*w0.y + wc*w0.z + wd*w0.w;
            b1 += wa*w1.x + wbv*w1.y + wc*w1.z + wd*w1.w;
            b2 += wa*w2.x + wbv*w2.y + wc*w2.z + wd*w2.w;
            b3 += wa*w3.x + wbv*w3.y + wc*w3.z + wd*w3.w;
        }
        p1k[pair*512 +   0 + c] = b0; p1k[pair*512 + 128 + c] = b1;
        p1k[pair*512 + 256 + c] = b2; p1k[pair*512 + 384 + c] = b3;
    }
    __syncthreads();
    s1a[tid]     = p1k[tid]     + p1k[512+tid]     + L::at(btok, tid & 127);
    s1a[tid+256] = p1k[tid+256] + p1k[768+tid]     + L::at(btok, (tid+256) & 127);
    __syncthreads();
    {   // s2[h][c] = s1_h @ Wv[:,c] + bv
        float b0=0.f,b1=0.f,b2=0.f,b3=0.f;
        #pragma unroll
        for (int k4 = 0; k4 < 64; k4 += 4) {
            int kk = pair*64 + k4;
            float wa = L::at(Wv,(long)kk*128+c),     wbv = L::at(Wv,(long)(kk+1)*128+c);
            float wc = L::at(Wv,(long)(kk+2)*128+c), wd  = L::at(Wv,(long)(kk+3)*128+c);
            float4 w0 = *(const float4*)&s1a[kk],     w1 = *(const float4*)&s1a[128+kk];
            float4 w2 = *(const float4*)&s1a[256+kk], w3 = *(const float4*)&s1a[384+kk];
            b0 += wa*w0.x + wbv*w0.y + wc*w0.z + wd*w0.w;
            b1 += wa*w1.x + wbv*w1.y + wc*w1.z + wd*w1.w;
            b2 += wa*w2.x + wbv*w2.y + wc*w2.z + wd*w2.w;
            b3 += wa*w3.x + wbv*w3.y + wc*w3.z + wd*w3.w;
        }
        p1k[pair*512 +   0 + c] = b0; p1k[pair*512 + 128 + c] = b1;
        p1k[pair*512 + 256 + c] = b2; p1k[pair*512 + 384 + c] = b3;
    }
    __syncthreads();
    s2a[tid]     = p1k[tid]     + p1k[512+tid] + L::at(bv, tid & 127);
    s2a[tid+256] = p1k[tid+256] + p1k[768+tid] + L::at(bv, (tid+256) & 127);
    __syncthreads();
    {   // ctx[o]= s2_h @ Wiv[:, o]
        int h = c >> 5;
        float acc = 0.f;
        #pragma unroll
        for (int k4 = 0; k4 < 64; k4 += 4) {
            int kk = pair*64 + k4;
            float4 s4 = *(const float4*)&s2a[h*128 + kk];
            acc += s4.x*L::at(Wiv,(long)kk*128+c)     + s4.y*L::at(Wiv,(long)(kk+1)*128+c)
                 + s4.z*L::at(Wiv,(long)(kk+2)*128+c) + s4.w*L::at(Wiv,(long)(kk+3)*128+c);
        }
        p1k[pair*128 + c] = acc;
    }
    __syncthreads();
    if (tid < 128) ctxa[tid] = p1k[tid] + p1k[128+tid] + L::at(biv, tid);
    __syncthreads();
    {   // ao = ctx @ Wo + bo
        float acc = 0.f;
        #pragma unroll
        for (int k4 = 0; k4 < 64; k4 += 4) {
            int kk = pair*64 + k4;
            float4 c4 = *(const float4*)&ctxa[kk];
            acc += c4.x*L::at(Wo,(long)kk*128+c)     + c4.y*L::at(Wo,(long)(kk+1)*128+c)
                 + c4.z*L::at(Wo,(long)(kk+2)*128+c) + c4.w*L::at(Wo,(long)(kk+3)*128+c);
        }
        p1k[pair*128 + c] = acc;
    }
    __syncthreads();
    if (tid < 128) aoa[tid] = p1k[tid] + p1k[128+tid] + L::at(bo, tid);
    __syncthreads();
    {   // y2 = ao @ Wco + bco
        float acc0 = 0.f, acc1 = 0.f;
        #pragma unroll
        for (int k = 0; k < 128; k += 4) {
            float4 a4 = *(const float4*)&aoa[k];
            acc0 += a4.x*L::at(Wco,(long)k*512+tid)     + a4.y*L::at(Wco,(long)(k+1)*512+tid)
                  + a4.z*L::at(Wco,(long)(k+2)*512+tid) + a4.w*L::at(Wco,(long)(k+3)*512+tid);
            acc1 += a4.x*L::at(Wco,(long)k*512+tid+256)     + a4.y*L::at(Wco,(long)(k+1)*512+tid+256)
                  + a4.z*L::at(Wco,(long)(k+2)*512+tid+256) + a4.w*L::at(Wco,(long)(k+3)*512+tid+256);
        }
        y2a[tid]     = acc0 + L::at(bco, tid);
        y2a[tid+256] = acc1 + L::at(bco, tid+256);
    }
    __syncthreads();
    {   // out[3] = y2 @ Wout + bout — wave shfl reduce, single barrier
        float ya = y2a[tid], yb = y2a[tid+256];
        float p0 = ya*L::at(Wout,(long)tid*3+0) + yb*L::at(Wout,(long)(tid+256)*3+0);
        float p1 = ya*L::at(Wout,(long)tid*3+1) + yb*L::at(Wout,(long)(tid+256)*3+1);
        float p2 = ya*L::at(Wout,(long)tid*3+2) + yb*L::at(Wout,(long)(tid+256)*3+2);
        #pragma unroll
        for (int mm = 1; mm < 64; mm <<= 1) {
            p0 += __shfl_xor(p0, mm, 64);
            p1 += __shfl_xor(p1, mm, 64);
            p2 += __shfl_xor(p2, mm, 64);
        }
        int wvv = tid >> 6, ln = tid & 63;
        if (ln == 0) { p1k[wvv*3+0] = p0; p1k[wvv*3+1] = p1; p1k[wvv*3+2] = p2; }
        __syncthreads();
        if (tid < 3) {
            float val = p1k[tid] + p1k[3+tid] + p1k[6+tid] + p1k[9+tid] + L::at(bout, tid);
            if (BF16) ((ushort_t*)out)[b*3+tid] = f2bf(val);
            else      ((float*)out)[b*3+tid] = val;
        }
    }
}

__global__ __launch_bounds__(256) void kE(
    float* ws,
    const void* Wtok, const void* btok, const void* Wv, const void* bv,
    const void* Wiv, const void* biv, const void* Wo, const void* bo,
    const void* Wco, const void* bco, const void* Wout, const void* bout,
    void* out)
{
    __shared__ float sh[3332];
    __shared__ int shi[32];
    if (*(const int*)(ws + WS_FLAG))
        kE_impl<true >(blockIdx.x, threadIdx.x, ws, Wtok,btok,Wv,bv,Wiv,biv,
                       Wo,bo,Wco,bco,Wout,bout,out,sh,shi);
    else
        kE_impl<false>(blockIdx.x, threadIdx.x, ws, Wtok,btok,Wv,bv,Wiv,biv,
                       Wo,bo,Wco,bco,Wout,bout,out,sh,shi);
}

// ---------------------------------------------------------------------------
extern "C" void kernel_launch(void* const* d_in, const int* in_sizes, int n_in,
                              void* d_out, int out_size, void* d_ws, size_t ws_size,
                              hipStream_t stream)
{
    const void* features = d_in[0];
    const int*  batch_idx= (const int*)d_in[1];
    const void* y_t      = d_in[2];
    const int*  t        = (const int*)d_in[3];
    // d_in[4] = N_max (unused)
    const void *Wtok=d_in[5],  *btok=d_in[6];
    const void *Wt  =d_in[7],  *bt  =d_in[8];
    const void *Win =d_in[9],  *bin_=d_in[10];
    const void *Wq  =d_in[11], *bq  =d_in[12];
    const void *Wk  =d_in[13], *bk  =d_in[14];
    const void *Wv  =d_in[15], *bv  =d_in[16];
    const void *Wiq =d_in[17], *biq =d_in[18];
    const void *Wik =d_in[19], *bik =d_in[20];
    const void *Wiv =d_in[21], *biv =d_in[22];
    const void *Wo  =d_in[23], *bo  =d_in[24];
    const void *Wco =d_in[25], *bco =d_in[26];
    const void *Wout=d_in[27], *bout=d_in[28];

    int N = in_sizes[0] / CENC;   // 131072
    float* ws = (float*)d_ws;

    kA<<<NB, 256, 0, stream>>>((const ushort_t*)features, y_t, t,
        Wt, bt, Win, bin_, Wq, bq, Wiq, biq, Wtok, btok, Wk, bk, Wik, bik, ws);
    kF<<<N / 256, 512, 0, stream>>>(features, batch_idx, ws);
    kE<<<NB, 256, 0, stream>>>(ws, Wtok, btok, Wv, bv, Wiv, biv, Wo, bo,
                               Wco, bco, Wout, bout, d_out);
}